// Round 2
// baseline (188.691 us; speedup 1.0000x reference)
//
#include <hip/hip_runtime.h>
#include <stdint.h>
#include <stddef.h>

#define GLOBAL_AS __attribute__((address_space(1)))
#define LDS_AS    __attribute__((address_space(3)))

typedef __bf16 bf16x8 __attribute__((ext_vector_type(8)));
typedef float  f32x4  __attribute__((ext_vector_type(4)));

// x(8,256,64,64) fp32, W(128,256,4,4), bias(128,4,4), stride 2 -> out(8,128,130,130) fp32
constexpr int NB = 8, CI = 256, H_ = 64, W_ = 64, CO = 128;
constexpr int OH = 130, OW = 130;
constexpr int PU = 65;     // per-parity output extent u,v in [0,65)
constexpr int PAD = 66;    // padded x extent (zero border ring)
constexpr int NPIX = PU * PU;        // 4225 flat pixels per (batch)
constexpr int NTILES = 34;           // ceil(4225/128)

constexpr size_t XPAD_ELEMS = (size_t)NB * PAD * PAD * CI;   // bf16
constexpr size_t XPAD_BYTES = XPAD_ELEMS * 2;                // 17,842,176
constexpr size_t WT_OFF     = XPAD_BYTES;                    // A_all offset
// A_all[512][1024]: row = py*256 + o*2 + px ; k = (a*2+c)*256 + i

__device__ __forceinline__ void gload_lds16(const void* g, void* l) {
  __builtin_amdgcn_global_load_lds((GLOBAL_AS void*)g, (LDS_AS void*)l, 16, 0, 0);
}

// ---- prep 1: x (b,i,h,w) fp32 -> x_padT[b][h+1][w+1][i] bf16 (borders zeroed by memset) ----
__global__ void prep_x(const float* __restrict__ x, __bf16* __restrict__ xp) {
  __shared__ float tile[64][65];
  const int h   = blockIdx.x;
  const int bat = blockIdx.y;
  const int t   = threadIdx.x;   // 256
  for (int ch = 0; ch < 4; ++ch) {
    const int i0 = ch * 64;
    const float* src = x + (((size_t)(bat * CI + i0)) * H_ + h) * W_;
    if (ch) __syncthreads();
#pragma unroll
    for (int r = 0; r < 4; ++r) {
      int ii = r * 16 + (t >> 4);
      int ww = (t & 15) * 4;
      float4 v = *(const float4*)(src + (size_t)ii * H_ * W_ + ww);
      tile[ii][ww] = v.x; tile[ii][ww + 1] = v.y; tile[ii][ww + 2] = v.z; tile[ii][ww + 3] = v.w;
    }
    __syncthreads();
    __bf16* dst = xp + ((size_t)(bat * PAD + h + 1) * PAD + 1) * CI + i0;
#pragma unroll
    for (int r = 0; r < 2; ++r) {
      int s  = r * 256 + t;
      int ww = s >> 3;
      int ig = (s & 7) * 8;
      bf16x8 o;
#pragma unroll
      for (int k = 0; k < 8; ++k) o[k] = (__bf16)tile[ig + k][ww];
      *(bf16x8*)(dst + (size_t)ww * CI + ig) = o;
    }
  }
}

// ---- prep 2: W (o,i,ky,kx) fp32 -> A_all[(py*256 + o*2+px)*1024 + (a*2+c)*256 + i] bf16 ----
__global__ void prep_w2(const float* __restrict__ w, __bf16* __restrict__ wt2) {
  int tid = blockIdx.x * 256 + threadIdx.x;      // [0, 2^19)
  int i   = tid & 255;
  int tap = (tid >> 8) & 3;
  int row = (tid >> 10) & 255;
  int py  = tid >> 18;
  int a = tap >> 1, c = tap & 1;
  int o = row >> 1, px = row & 1;
  wt2[tid] = (__bf16)w[(size_t)(o * CI + i) * 16 + (py + 2 * a) * 4 + (px + 2 * c)];
}

// ---- main: fused GEMM. Block: BM=256 (one py; rows o*2+px) x BN=128 flat px, K=1024 ----
__global__ __launch_bounds__(512) void deconv_mfma(
    const __bf16* __restrict__ xp, const __bf16* __restrict__ wt2,
    const float* __restrict__ bias, float* __restrict__ out) {
  // grid: wg = ntile + 34*(bat + 8*py) ; 34*8*2 = 544
  const int wg    = blockIdx.x;
  const int nt_i  = wg % NTILES;
  const int bat   = (wg / NTILES) % 8;
  const int py    = wg / (NTILES * 8);
  const int nBase = nt_i * 128;

  __shared__ alignas(16) __bf16 lds[2][12288]; // per buf: A [0,8192) (256m x 32k), B [8192,12288) (128n x 32k)

  const int t    = threadIdx.x;
  const int wid  = t >> 6, lane = t & 63;
  const int lr   = lane & 15, kg = lane >> 4;
  const int wr   = wid >> 1, wc = wid & 1;

  // staging invariants: thread t stages A chunks q=t,q=t+512 and B chunk q=t
  const int mA   = t >> 2;                       // row 0..127 (chunk2: +128, same swizzle phase)
  const int kstA = (t & 3) ^ ((mA >> 1) & 3);    // logical k-group at this phys slot (involution)
  const __bf16* srcA = wt2 + ((size_t)py * 256 + mA) * 1024 + kstA * 8;

  int pix = nBase + mA;
  if (pix > NPIX - 1) pix = NPIX - 1;            // tail clamp (finite garbage cols, never written)
  const int uB = pix / PU, vB = pix % PU;
  const __bf16* srcB = xp + ((size_t)(bat * PAD + uB + 1) * PAD + (vB + 1)) * CI + kstA * 8;

  // fragment read offsets (elems within buffer), matching the staging swizzle
  const int swz = (lr >> 1) & 3;
  int offA[4], offB[4];
#pragma unroll
  for (int mt = 0; mt < 4; ++mt)
    offA[mt] = (wr * 64 + mt * 16 + lr) * 32 + ((kg ^ swz) * 8);
#pragma unroll
  for (int nt = 0; nt < 4; ++nt)
    offB[nt] = 8192 + (wc * 64 + nt * 16 + lr) * 32 + ((kg ^ swz) * 8);

  f32x4 acc[4][4] = {};

  auto stage = [&](int buf, int s) {
    const int ic = (s & 7) * 32;
    const int a  = s >> 4, c = (s >> 3) & 1;
    const __bf16* sa = srcA + s * 32;                              // A k-layout is linear in k
    const __bf16* sb = srcB + ic - (size_t)(a * PAD + c) * CI;     // tap shift on the pixel
    __bf16* l = &lds[buf][0];
    gload_lds16(sa,                    l + (size_t)t * 8);
    gload_lds16(sa + 128 * 1024,       l + (size_t)t * 8 + 4096);
    gload_lds16(sb,                    l + 8192 + (size_t)t * 8);
  };

  stage(0, 0);
  __syncthreads();
  int cur = 0;
  for (int s = 0; s < 32; ++s) {
    if (s < 31) stage(cur ^ 1, s + 1);
    const __bf16* base = &lds[cur][0];
    bf16x8 af[4], bf[4];
#pragma unroll
    for (int mt = 0; mt < 4; ++mt) af[mt] = *(const bf16x8*)(base + offA[mt]);
#pragma unroll
    for (int nt = 0; nt < 4; ++nt) bf[nt] = *(const bf16x8*)(base + offB[nt]);
#pragma unroll
    for (int mt = 0; mt < 4; ++mt)
#pragma unroll
      for (int nt = 0; nt < 4; ++nt)
        acc[mt][nt] = __builtin_amdgcn_mfma_f32_16x16x32_bf16(af[mt], bf[nt], acc[mt][nt], 0, 0, 0);
    __syncthreads();
    cur ^= 1;
  }

  // ---- epilogue: rows r,r+1 are px=0,1 of the same o -> dense float2 stores ----
#pragma unroll
  for (int mt = 0; mt < 4; ++mt) {
    const int rbase = wr * 64 + mt * 16 + kg * 4;  // D row = (lane>>4)*4 + r [m89-verified]
    const int o0 = rbase >> 1, o1 = o0 + 1;
#pragma unroll
    for (int nt = 0; nt < 4; ++nt) {
      const int n = nBase + wc * 64 + nt * 16 + lr;
      if (n < NPIX) {
        const int u = n / PU, v = n % PU;
        const int oy = 2 * u + py;
        const bool a0 = (u <= 63), a1 = (u >= 1);
        const bool c0 = (v <= 63), c1 = (v >= 1);
        // bias sums for (o, px): taps (a,c) valid per source-pixel existence
        auto bs = [&](int o, int px) {
          const float* bp = bias + (size_t)o * 16;
          float s0 = 0.f;
          if (a0 && c0) s0 += bp[py * 4 + px];
          if (a0 && c1) s0 += bp[py * 4 + px + 2];
          if (a1 && c0) s0 += bp[(py + 2) * 4 + px];
          if (a1 && c1) s0 += bp[(py + 2) * 4 + px + 2];
          return s0;
        };
        const size_t b0 = ((size_t)(bat * CO + o0) * OH + oy) * OW + 2 * v;
        const size_t b1 = ((size_t)(bat * CO + o1) * OH + oy) * OW + 2 * v;
        float2 w0, w1;
        w0.x = acc[mt][nt][0] + bs(o0, 0);
        w0.y = acc[mt][nt][1] + bs(o0, 1);
        w1.x = acc[mt][nt][2] + bs(o1, 0);
        w1.y = acc[mt][nt][3] + bs(o1, 1);
        *(float2*)(out + b0) = w0;
        *(float2*)(out + b1) = w1;
      }
    }
  }
}

extern "C" void kernel_launch(void* const* d_in, const int* in_sizes, int n_in,
                              void* d_out, int out_size, void* d_ws, size_t ws_size,
                              hipStream_t stream) {
  const float* x    = (const float*)d_in[0];
  const float* w    = (const float*)d_in[1];
  const float* bias = (const float*)d_in[2];
  float* out = (float*)d_out;
  char* ws = (char*)d_ws;
  __bf16* xpad = (__bf16*)ws;
  __bf16* wt2  = (__bf16*)(ws + WT_OFF);

  hipMemsetAsync(xpad, 0, XPAD_BYTES, stream);          // zero border ring (interior overwritten)
  prep_x<<<dim3(64, 8), 256, 0, stream>>>(x, xpad);
  prep_w2<<<dim3(2048), 256, 0, stream>>>(w, wt2);
  deconv_mfma<<<dim3(544), 512, 0, stream>>>(xpad, wt2, bias, out);
}